// Round 4
// baseline (390.272 us; speedup 1.0000x reference)
//
#include <hip/hip_runtime.h>

// x: [8, 1, 160, 160, 160] fp32; log_sigma: [3] fp32; out: scalar fp32.
// loss = -(sum over 3816 (axis,b,pair) of exp(-sq/(2*sigma_axis^2))) / 3816.
//
// R10: AMPLIFICATION PROBE (deliberate diagnostic). Three structurally
// different diff3 kernels (R6 register-landing, R7 prefetch+bounds, R9
// global_load_lds staging) all land in a 196-208us band, and diff3 has
// NEVER appeared in rocprof top-5 (every slot = the harness's 524MB/75us
// re-poison fill; diff3 < 75us, otherwise unknown). Two models fit:
//   A: 1 fill timed -> diff3 ~60-70us, ~100us controllable.
//   B: 2 fills timed -> diff3 ~20us (HBM floor), ~25us controllable.
// This round: exact R6 body (best measured, 195.9us) with the slice loop
// wrapped in a 12-pass loop. Pass 0 = real compute from x (identical
// behavior + flush). Passes 1-11 = dummy reads of the same volume from xd
// (= x at launch; distinct formal pointer -> no CSE vs pass 0) with batch
// rotated by p (p-dependent address -> no LICM), accumulators kept live
// via asm sinks (DCE rule #17). Amplified diff3 (~120-420us) lands in
// top-5 -> first-ever VGPR/Occ/VALUBusy/FETCH_SIZE for this kernel, and:
//   PL3 = (total - 196)/11;  P1 = amp_row_dur - 11*PL3;  BW1 = FETCH/P1.
// reduce/final verbatim R6. Output path untouched.

constexpr int Wd4 = 40;              // float4 per row
constexpr int SLICE4 = 6400;         // float4 per slice
constexpr long BSTR4 = 160L * 6400;  // float4 per batch
constexpr int NB = 8;
constexpr int NPAIR = 159;
constexpr int NKEY = 3 * NB * NPAIR;   // 3816
constexpr int SLOT = 200;              // floats/slot: [0..4]=D [5..36]=H [37..196]=W
constexpr int NBLK = NB * 160;         // 8 b x 32 d-segs x 5 h-chunks = 1280
constexpr int PART_OFF = NBLK * SLOT;  // float offset of reduce partials in ws
constexpr int NFIN = 60;
constexpr int NPASS = 12;              // 1 real + 11 dummy (L3-warm) passes

__device__ __forceinline__ float sq4(const float4& a, const float4& c) {
    float e0 = a.x - c.x, e1 = a.y - c.y, e2 = a.z - c.z, e3 = a.w - c.w;
    return e0 * e0 + e1 * e1 + e2 * e2 + e3 * e3;
}

// 1280 blocks x 320 threads. bid -> (b, ds 0..31, hc 0..4). Thread: c4=t%40,
// rp=t/40 owns rows h0+4rp+{0..3}. Slices d0..d0+4 owned, d0+5 halo (v only).
__global__ __launch_bounds__(320) void diff3_kernel(const float* x,
                                                    const float* xd,
                                                    float* __restrict__ ws) {
    __shared__ float lds[1504];  // H: [0..1311] 32 keys*41; D: [1472..1496]; W reuses [0..1439]

    const int t = threadIdx.x;
    const int bid = blockIdx.x;
    const int b = bid / 160;
    const int r2 = bid % 160;
    const int ds = r2 / 5;     // d-segment, d0 = 5*ds
    const int hc = r2 % 5;     // h-chunk,  h0 = 32*hc
    const int d0 = ds * 5, h0 = hc * 32;
    const bool lastSeg = (ds == 31);

    const int c4 = t % 40;
    const int rp = t / 40;                  // 0..7
    const int lane = t & 63;
    const int wv = t >> 6;                  // wave 0..4
    const bool hOK = !(hc == 4 && rp == 7); // row h0+4rp+4 <= 159
    const bool sOK = (c4 < 39);
    const bool fixB = (lane == 63) && sOK;  // shfl partner in next wave -> load

    const size_t toff = (size_t)d0 * SLICE4 + (size_t)(h0 + 4 * rp) * Wd4 + c4;
    const float4* base0 = (const float4*)x + (size_t)b * BSTR4 + toff;

#pragma unroll 1
    for (int p = 0; p < NPASS; ++p) {
        // p==0: real pass (own batch, from x). p>0: dummy pass (batch rotated
        // by p, from xd) — same volume, p-dependent address, un-CSE-able.
        const float4* base = (p == 0)
            ? base0
            : (const float4*)xd + (size_t)((b + p) & 7) * BSTR4 + toff;

        float aW[4] = {0.f, 0.f, 0.f, 0.f};
        float aH[4] = {0.f, 0.f, 0.f, 0.f};
        float aD[5] = {0.f, 0.f, 0.f, 0.f, 0.f};
        float4 p0, p1, p2, p3;

#pragma unroll
        for (int it = 0; it < 5; ++it) {
            const float4* sp = base + it * SLICE4;
            const float4 v0 = sp[0];
            const float4 v1 = sp[Wd4];
            const float4 v2 = sp[2 * Wd4];
            const float4 v3 = sp[3 * Wd4];
            float4 hv;
            if (hOK) hv = sp[4 * Wd4];
            float bx0 = 0.f, bx1 = 0.f, bx2 = 0.f, bx3 = 0.f;
            if (fixB) {  // cross-wave w-boundary partner: scalar loads (4 thr/block)
                bx0 = ((const float*)(sp))[4];
                bx1 = ((const float*)(sp + Wd4))[4];
                bx2 = ((const float*)(sp + 2 * Wd4))[4];
                bx3 = ((const float*)(sp + 3 * Wd4))[4];
            }
            // w-boundary partner .x from lane+1 (same row, next float4)
            float s0 = __shfl_down(v0.x, 1, 64); if (fixB) s0 = bx0;
            float s1 = __shfl_down(v1.x, 1, 64); if (fixB) s1 = bx1;
            float s2 = __shfl_down(v2.x, 1, 64); if (fixB) s2 = bx2;
            float s3 = __shfl_down(v3.x, 1, 64); if (fixB) s3 = bx3;

            float dw;
            dw = v0.y - v0.x; aW[0] += dw * dw;
            dw = v0.z - v0.y; aW[1] += dw * dw;
            dw = v0.w - v0.z; aW[2] += dw * dw;
            dw = v1.y - v1.x; aW[0] += dw * dw;
            dw = v1.z - v1.y; aW[1] += dw * dw;
            dw = v1.w - v1.z; aW[2] += dw * dw;
            dw = v2.y - v2.x; aW[0] += dw * dw;
            dw = v2.z - v2.y; aW[1] += dw * dw;
            dw = v2.w - v2.z; aW[2] += dw * dw;
            dw = v3.y - v3.x; aW[0] += dw * dw;
            dw = v3.z - v3.y; aW[1] += dw * dw;
            dw = v3.w - v3.z; aW[2] += dw * dw;
            if (sOK) {
                dw = s0 - v0.w; aW[3] += dw * dw;
                dw = s1 - v1.w; aW[3] += dw * dw;
                dw = s2 - v2.w; aW[3] += dw * dw;
                dw = s3 - v3.w; aW[3] += dw * dw;
            }
            // h: 3 register-local pairs + 1 via hv
            aH[0] += sq4(v1, v0);
            aH[1] += sq4(v2, v1);
            aH[2] += sq4(v3, v2);
            if (hOK) aH[3] += sq4(hv, v3);
            // d: vs previous slice (rolling regs)
            if (it > 0)
                aD[it - 1] += sq4(v0, p0) + sq4(v1, p1) + sq4(v2, p2) + sq4(v3, p3);
            p0 = v0; p1 = v1; p2 = v2; p3 = v3;  // SSA under full unroll
        }
        if (!lastSeg) {  // halo slice d0+5: v-only, completes pair key d0+4
            const float4* sp = base + 5 * SLICE4;
            aD[4] = sq4(sp[0], p0) + sq4(sp[Wd4], p1) + sq4(sp[2 * Wd4], p2) + sq4(sp[3 * Wd4], p3);
        }

        if (p == 0) {
            // ---- flush (R6 verbatim). Phase 1: H per-key scratch + D wave-reduce.
#pragma unroll
            for (int j = 0; j < 4; ++j) lds[(4 * rp + j) * 41 + c4] = aH[j];
#pragma unroll
            for (int j = 0; j < 5; ++j) {
                float dd = aD[j];
                for (int off = 32; off > 0; off >>= 1) dd += __shfl_down(dd, off, 64);
                if (lane == 0) lds[1472 + j * 5 + wv] = dd;
            }
            __syncthreads();
            float hsum = 0.f, dsum = 0.f;
            if (t < 32) {
                const float* src = &lds[t * 41];
                for (int i = 0; i < 40; ++i) hsum += src[i];
            }
            if (t < 5) {
                for (int w2 = 0; w2 < 5; ++w2) dsum += lds[1472 + t * 5 + w2];
            }
            __syncthreads();  // H region reads done; reuse for W
            // Phase 2: W per-key scratch (key 4c4+j, 8 contributors rp).
#pragma unroll
            for (int j = 0; j < 4; ++j) lds[(4 * c4 + j) * 9 + rp] = aW[j];
            __syncthreads();
            float wsum = 0.f;
            if (t < 160) {
                const float* src = &lds[t * 9];
                for (int i = 0; i < 8; ++i) wsum += src[i];
            }
            // Private slot write (no atomics; every slot float written).
            float* slot = ws + (size_t)bid * SLOT;
            if (t < 5)   slot[t] = dsum;
            if (t < 32)  slot[5 + t] = hsum;
            if (t < 160) slot[37 + t] = wsum;
        } else {
            // dummy pass: keep accumulators live without cost (no DCE).
#pragma unroll
            for (int j = 0; j < 4; ++j) asm volatile("" :: "v"(aW[j]));
#pragma unroll
            for (int j = 0; j < 4; ++j) asm volatile("" :: "v"(aH[j]));
#pragma unroll
            for (int j = 0; j < 5; ++j) asm volatile("" :: "v"(aD[j]));
        }
    }
}

// 60 blocks x 64 threads: one thread per (axis,b,pair); sums contributing slots.
__global__ __launch_bounds__(64) void reduce_kernel(const float* __restrict__ ws,
                                                    const float* __restrict__ log_sigma,
                                                    float* __restrict__ part) {
    const int gk = blockIdx.x * 64 + threadIdx.x;
    float kv = 0.f;
    if (gk < NKEY) {
        const int a = gk / (NB * NPAIR);
        const int rem = gk % (NB * NPAIR);
        const int b = rem / NPAIR;
        const int k = rem % NPAIR;
        const float f = -0.5f * expf(-2.f * log_sigma[a]);  // -1/(2*sigma^2)
        const float* bb = ws + (size_t)b * 160 * SLOT;
        float val = 0.f;
        if (a == 0) {        // D: key k -> ds=k/5, j=k%5, sum over 5 hc
            const int ds = k / 5, j = k % 5;
            const float* p = bb + (size_t)(ds * 5) * SLOT + j;
            for (int hc = 0; hc < 5; ++hc) val += p[hc * SLOT];
        } else if (a == 1) { // H: key k -> hc=k/32, kk=k%32, sum over 32 ds
            const int hc = k / 32, kk = k % 32;
            const float* p = bb + (size_t)hc * SLOT + 5 + kk;
            for (int ds = 0; ds < 32; ++ds) val += p[(size_t)(ds * 5) * SLOT];
        } else {             // W: key k, sum over all 160 (ds,hc)
            const float* p = bb + 37 + k;
            for (int i = 0; i < 160; ++i) val += p[(size_t)i * SLOT];
        }
        kv = expf(val * f);
    }
    for (int off = 32; off > 0; off >>= 1) kv += __shfl_down(kv, off, 64);
    if (threadIdx.x == 0) part[blockIdx.x] = kv;
}

__global__ __launch_bounds__(64) void final_kernel(const float* __restrict__ part,
                                                   float* __restrict__ out) {
    float v = (threadIdx.x < NFIN) ? part[threadIdx.x] : 0.f;
    for (int off = 32; off > 0; off >>= 1) v += __shfl_down(v, off, 64);
    if (threadIdx.x == 0) out[0] = -v / (float)NKEY;
}

extern "C" void kernel_launch(void* const* d_in, const int* in_sizes, int n_in,
                              void* d_out, int out_size, void* d_ws, size_t ws_size,
                              hipStream_t stream) {
    const float* x = (const float*)d_in[0];
    const float* log_sigma = (const float*)d_in[1];
    float* out = (float*)d_out;
    float* ws = (float*)d_ws;

    diff3_kernel<<<NBLK, 320, 0, stream>>>(x, x, ws);
    reduce_kernel<<<NFIN, 64, 0, stream>>>(ws, log_sigma, ws + PART_OFF);
    final_kernel<<<1, 64, 0, stream>>>(ws + PART_OFF, out);
}

// Round 5
// 200.787 us; speedup vs baseline: 1.9437x; 1.9437x over previous
//
#include <hip/hip_runtime.h>

// x: [8, 1, 160, 160, 160] fp32; log_sigma: [3] fp32; out: scalar fp32.
// loss = -(sum over 3816 (axis,b,pair) of exp(-sq/(2*sigma_axis^2))) / 3816.
//
// R11: MAX-MLP LOAD PHASE. R10's amplification probe finally measured diff3:
// VGPR=68, cold pass ~65us (190MB @ ~2.9 TB/s), L3-warm pass 17.7us (~10
// TB/s logical) -> the body is fine; the cold pass is latency x MLP bound.
// Little's law: 2.9 TB/s x 430ns ~= 4.9KB inflight/CU (~5 wave-loads) vs
// ~11KB needed for 6.3 TB/s. The compiler's pressure-minimizing schedule
// (68 VGPR!) keeps only ~1-2 slices in flight per wave. Fix: issue ALL 29
// vector loads + 20 boundary scalars in one pure load phase into named
// registers, pinned with sched_barrier(0) so the scheduler can't sink them
// back toward uses. ~165 VGPR -> 3 waves/SIMD, ~29KB inflight per wave.
// Also (R9-validated): fuse the tail — diff3 zeroes out, reduce atomicAdds
// -exp(val*f)/NKEY; final_kernel and one launch gap removed.
// Tiling, math, flush, ws contract identical to R6 (best measured, 195.9us).

constexpr int Wd4 = 40;              // float4 per row
constexpr int SLICE4 = 6400;         // float4 per slice
constexpr long BSTR4 = 160L * 6400;  // float4 per batch
constexpr int NB = 8;
constexpr int NPAIR = 159;
constexpr int NKEY = 3 * NB * NPAIR;   // 3816
constexpr int SLOT = 200;              // floats/slot: [0..4]=D [5..36]=H [37..196]=W
constexpr int NBLK = NB * 160;         // 8 b x 32 d-segs x 5 h-chunks = 1280
constexpr int NRED = 60;               // 60*64 = 3840 >= 3816 keys

__device__ __forceinline__ float sq4(const float4& a, const float4& c) {
    float e0 = a.x - c.x, e1 = a.y - c.y, e2 = a.z - c.z, e3 = a.w - c.w;
    return e0 * e0 + e1 * e1 + e2 * e2 + e3 * e3;
}

// 1280 blocks x 320 threads. bid -> (b, ds 0..31, hc 0..4). Thread: c4=t%40,
// rp=t/40 owns rows h0+4rp+{0..3}. Slices d0..d0+4 owned, d0+5 halo (v only).
__global__ __launch_bounds__(320) void diff3_kernel(const float* __restrict__ x,
                                                    float* __restrict__ ws,
                                                    float* __restrict__ out) {
    __shared__ float lds[1504];  // H: [0..1311] 32 keys*41; D: [1472..1496]; W reuses [0..1439]

    const int t = threadIdx.x;
    const int bid = blockIdx.x;
    const int b = bid / 160;
    const int r2 = bid % 160;
    const int ds = r2 / 5;     // d-segment, d0 = 5*ds
    const int hc = r2 % 5;     // h-chunk,  h0 = 32*hc
    const int d0 = ds * 5, h0 = hc * 32;
    const bool lastSeg = (ds == 31);

    const int c4 = t % 40;
    const int rp = t / 40;                  // 0..7
    const int lane = t & 63;
    const int wv = t >> 6;                  // wave 0..4
    const bool hOK = !(hc == 4 && rp == 7); // row h0+4rp+4 <= 159
    const bool sOK = (c4 < 39);
    const bool fixB = (lane == 63) && sOK;  // shfl partner in next wave -> load

    if (bid == 0 && t == 0) out[0] = 0.f;   // reduce_kernel accumulates after us

    const float4* base = (const float4*)x + (size_t)b * BSTR4 + (size_t)d0 * SLICE4
                       + (size_t)(h0 + 4 * rp) * Wd4 + c4;

    // ==== LOAD PHASE: issue everything back-to-back (MLP), in consumption order.
    float4 v[5][4];   // [slice][row]
    float4 hv[5];     // h-halo row per slice
    float  bx[5][4];  // w-boundary partner scalar per slice/row (fixB lanes only)
    float4 nx[4];     // d-halo slice rows
#pragma unroll
    for (int it = 0; it < 5; ++it) {
        const float4* sp = base + it * SLICE4;
        v[it][0] = sp[0];
        v[it][1] = sp[Wd4];
        v[it][2] = sp[2 * Wd4];
        v[it][3] = sp[3 * Wd4];
        if (hOK) hv[it] = sp[4 * Wd4];
        if (fixB) {
            const float* f = (const float*)sp;
            bx[it][0] = f[4];
            bx[it][1] = f[4 + 160];
            bx[it][2] = f[4 + 320];
            bx[it][3] = f[4 + 480];
        }
    }
    if (!lastSeg) {
        const float4* sp = base + 5 * SLICE4;
        nx[0] = sp[0];
        nx[1] = sp[Wd4];
        nx[2] = sp[2 * Wd4];
        nx[3] = sp[3 * Wd4];
    }
    __builtin_amdgcn_sched_barrier(0);  // pin: no compute hoisted above, no load sunk below

    // ==== COMPUTE PHASE (R6 math, array-indexed, static indices only).
    float aW[4] = {0.f, 0.f, 0.f, 0.f};
    float aH[4] = {0.f, 0.f, 0.f, 0.f};
    float aD[5] = {0.f, 0.f, 0.f, 0.f, 0.f};

#pragma unroll
    for (int it = 0; it < 5; ++it) {
        // w-boundary partner .x from lane+1 (same row, next float4)
        float s0 = __shfl_down(v[it][0].x, 1, 64); if (fixB) s0 = bx[it][0];
        float s1 = __shfl_down(v[it][1].x, 1, 64); if (fixB) s1 = bx[it][1];
        float s2 = __shfl_down(v[it][2].x, 1, 64); if (fixB) s2 = bx[it][2];
        float s3 = __shfl_down(v[it][3].x, 1, 64); if (fixB) s3 = bx[it][3];

        float dw;
        dw = v[it][0].y - v[it][0].x; aW[0] += dw * dw;
        dw = v[it][0].z - v[it][0].y; aW[1] += dw * dw;
        dw = v[it][0].w - v[it][0].z; aW[2] += dw * dw;
        dw = v[it][1].y - v[it][1].x; aW[0] += dw * dw;
        dw = v[it][1].z - v[it][1].y; aW[1] += dw * dw;
        dw = v[it][1].w - v[it][1].z; aW[2] += dw * dw;
        dw = v[it][2].y - v[it][2].x; aW[0] += dw * dw;
        dw = v[it][2].z - v[it][2].y; aW[1] += dw * dw;
        dw = v[it][2].w - v[it][2].z; aW[2] += dw * dw;
        dw = v[it][3].y - v[it][3].x; aW[0] += dw * dw;
        dw = v[it][3].z - v[it][3].y; aW[1] += dw * dw;
        dw = v[it][3].w - v[it][3].z; aW[2] += dw * dw;
        if (sOK) {
            dw = s0 - v[it][0].w; aW[3] += dw * dw;
            dw = s1 - v[it][1].w; aW[3] += dw * dw;
            dw = s2 - v[it][2].w; aW[3] += dw * dw;
            dw = s3 - v[it][3].w; aW[3] += dw * dw;
        }
        // h: 3 register-local pairs + 1 via hv
        aH[0] += sq4(v[it][1], v[it][0]);
        aH[1] += sq4(v[it][2], v[it][1]);
        aH[2] += sq4(v[it][3], v[it][2]);
        if (hOK) aH[3] += sq4(hv[it], v[it][3]);
        // d: vs previous slice
        if (it > 0)
            aD[it - 1] += sq4(v[it][0], v[it - 1][0]) + sq4(v[it][1], v[it - 1][1])
                        + sq4(v[it][2], v[it - 1][2]) + sq4(v[it][3], v[it - 1][3]);
    }
    if (!lastSeg) {  // d-halo slice completes pair key d0+4
        aD[4] = sq4(nx[0], v[4][0]) + sq4(nx[1], v[4][1])
              + sq4(nx[2], v[4][2]) + sq4(nx[3], v[4][3]);
    }

    // ---- flush (R6 verbatim). Phase 1: H per-key scratch + D wave-reduce.
#pragma unroll
    for (int j = 0; j < 4; ++j) lds[(4 * rp + j) * 41 + c4] = aH[j];
#pragma unroll
    for (int j = 0; j < 5; ++j) {
        float dd = aD[j];
        for (int off = 32; off > 0; off >>= 1) dd += __shfl_down(dd, off, 64);
        if (lane == 0) lds[1472 + j * 5 + wv] = dd;
    }
    __syncthreads();
    float hsum = 0.f, dsum = 0.f;
    if (t < 32) {
        const float* src = &lds[t * 41];
        for (int i = 0; i < 40; ++i) hsum += src[i];
    }
    if (t < 5) {
        for (int w2 = 0; w2 < 5; ++w2) dsum += lds[1472 + t * 5 + w2];
    }
    __syncthreads();  // H region reads done; reuse for W
    // Phase 2: W per-key scratch (key 4c4+j, 8 contributors rp).
#pragma unroll
    for (int j = 0; j < 4; ++j) lds[(4 * c4 + j) * 9 + rp] = aW[j];
    __syncthreads();
    float wsum = 0.f;
    if (t < 160) {
        const float* src = &lds[t * 9];
        for (int i = 0; i < 8; ++i) wsum += src[i];
    }
    // Private slot write (no atomics; every slot float written).
    float* slot = ws + (size_t)bid * SLOT;
    if (t < 5)   slot[t] = dsum;
    if (t < 32)  slot[5 + t] = hsum;
    if (t < 160) slot[37 + t] = wsum;
}

// 60 blocks x 64 threads: one thread per (axis,b,pair); sums contributing
// slots, then atomicAdds -exp(val*f)/NKEY into out (zeroed by diff3;
// stream order guarantees visibility). R9-validated tail fusion.
__global__ __launch_bounds__(64) void reduce_kernel(const float* __restrict__ ws,
                                                    const float* __restrict__ log_sigma,
                                                    float* __restrict__ out) {
    const int gk = blockIdx.x * 64 + threadIdx.x;
    float kv = 0.f;
    if (gk < NKEY) {
        const int a = gk / (NB * NPAIR);
        const int rem = gk % (NB * NPAIR);
        const int b = rem / NPAIR;
        const int k = rem % NPAIR;
        const float f = -0.5f * expf(-2.f * log_sigma[a]);  // -1/(2*sigma^2)
        const float* bb = ws + (size_t)b * 160 * SLOT;
        float val = 0.f;
        if (a == 0) {        // D: key k -> ds=k/5, j=k%5, sum over 5 hc
            const int dss = k / 5, j = k % 5;
            const float* p = bb + (size_t)(dss * 5) * SLOT + j;
            for (int hcc = 0; hcc < 5; ++hcc) val += p[hcc * SLOT];
        } else if (a == 1) { // H: key k -> hc=k/32, kk=k%32, sum over 32 ds
            const int hcc = k / 32, kk = k % 32;
            const float* p = bb + (size_t)hcc * SLOT + 5 + kk;
            for (int dss = 0; dss < 32; ++dss) val += p[(size_t)(dss * 5) * SLOT];
        } else {             // W: key k, sum over all 160 (ds,hc)
            const float* p = bb + 37 + k;
            for (int i = 0; i < 160; ++i) val += p[(size_t)i * SLOT];
        }
        kv = expf(val * f);
    }
    for (int off = 32; off > 0; off >>= 1) kv += __shfl_down(kv, off, 64);
    if (threadIdx.x == 0) atomicAdd(out, -kv / (float)NKEY);
}

extern "C" void kernel_launch(void* const* d_in, const int* in_sizes, int n_in,
                              void* d_out, int out_size, void* d_ws, size_t ws_size,
                              hipStream_t stream) {
    const float* x = (const float*)d_in[0];
    const float* log_sigma = (const float*)d_in[1];
    float* out = (float*)d_out;
    float* ws = (float*)d_ws;

    diff3_kernel<<<NBLK, 320, 0, stream>>>(x, ws, out);
    reduce_kernel<<<NRED, 64, 0, stream>>>(ws, log_sigma, out);
}